// Round 9
// baseline (313.223 us; speedup 1.0000x reference)
//
#include <hip/hip_runtime.h>
#include <math.h>

// EdgeGAT: B=8, OP=400, MA=200, F=64. f32 in/out, adj int32.
// z read ONCE, fully coalesced in native [b][n][m][f] layout.
// Block = (b, n-chunk CN=10, m-tile MT=20). Stage z-tile to LDS (68-float row
// stride), thread-per-pair scalar scores (no cross-lane ops), per-(m,chunk)
// flash partials {v,u,M,L} -> ws; combine rescales + epilogue.
#define B_   8
#define OP_  400
#define MA_  200
#define CN   10           // n rows per chunk
#define MT   20           // m cols per tile
#define NCH  40           // OP_/CN chunks per (b,m)
#define NMT  10           // MA_/MT m-tiles
#define PSTR 130          // partial: v[64] u[64] M L
#define NEGM -1.0e30f     // finite mask sentinel

// ---------------- kernel 1: precompute (wave-per-row) ----------------
// w_e = W_edge@a_edge ; e_op[b,n] = x[b,n,:].(W_op@a_op) ; e_ma[b,m] = y[b,m,:].(W_ma@a_ma)
__global__ __launch_bounds__(256) void precompute_k(
    const float* __restrict__ x, const float* __restrict__ y,
    const float* __restrict__ Wop, const float* __restrict__ Wma,
    const float* __restrict__ Wedge, const float* __restrict__ att,
    float* __restrict__ ws_we, float* __restrict__ ws_eop, float* __restrict__ ws_ema)
{
    __shared__ float w_s[192];
    const int tid = threadIdx.x, wv = tid >> 6, ln = tid & 63;
    if (tid < 192) {
        const int which = tid >> 6, i = tid & 63;
        const float* W = (which == 0) ? Wop : ((which == 1) ? Wma : Wedge);
        const float* a = att + which * 64;
        float acc = 0.f;
        #pragma unroll 8
        for (int f = 0; f < 64; ++f) acc = fmaf(W[i * 64 + f], a[f], acc);
        w_s[tid] = acc;
    }
    __syncthreads();
    if (blockIdx.x == 0 && tid < 64) ws_we[tid] = w_s[128 + tid];

    const int row = blockIdx.x * 4 + wv;           // 0 .. 4799
    if (row < B_ * OP_) {
        float s = x[(size_t)row * 64 + ln] * w_s[ln];
        #pragma unroll
        for (int o = 32; o > 0; o >>= 1) s += __shfl_xor(s, o, 64);
        if (ln == 0) ws_eop[row] = s;
    } else if (row < B_ * OP_ + B_ * MA_) {
        const int r2 = row - B_ * OP_;
        float s = y[(size_t)r2 * 64 + ln] * w_s[64 + ln];
        #pragma unroll
        for (int o = 32; o > 0; o >>= 1) s += __shfl_xor(s, o, 64);
        if (ln == 0) ws_ema[r2] = s;
    }
}

// ---------------- kernel 2: z-tile pass (block = (b, chunk, m-tile)) ----------------
__global__ __launch_bounds__(256) void gat_tile(
    const float* __restrict__ x, const float* __restrict__ z,
    const int* __restrict__ adj,
    const float* __restrict__ ws_we, const float* __restrict__ ws_eop,
    const float* __restrict__ ws_ema, float* __restrict__ part)
{
    __shared__ float4 z4[200 * 17];   // 54400 B: row p=i*MT+j, 17 float4 (68 f) stride
    __shared__ float  sc[200];        // scores, index i*MT+j
    __shared__ float  xt[CN * 64];    // x tile
    __shared__ float  we_s[64];       // w_e
    __shared__ float  eop_s[CN];
    __shared__ float  ema_s[MT];
    __shared__ int    adj_s[200];

    const float* zf = (const float*)z4;   // scalar view, row stride 68 floats

    const int tid = threadIdx.x, wv = tid >> 6, ln = tid & 63;
    const int bid = blockIdx.x;
    const int mt = bid % NMT;
    const int ch = (bid / NMT) % NCH;
    const int b  = bid / (NMT * NCH);
    const int n0 = ch * CN, m0 = mt * MT;

    // ---- stage z tile: slice i = 1280 contiguous floats (20 m x 64 f) ----
    for (int c = tid; c < CN * MT * 16; c += 256) {   // 3200 float4
        const int i = c / (MT * 16);                  // n-row in chunk
        const int r = c % (MT * 16);                  // float4 within slice
        const int j = r / 16;                         // m-col in tile
        const int k = r % 16;                         // float4 within row
        const float* zs = z + (((size_t)(b * OP_ + n0 + i)) * MA_ + m0) * 64;
        z4[(i * MT + j) * 17 + k] = *(const float4*)(zs + r * 4);
    }
    for (int c = tid; c < CN * 64; c += 256)
        xt[c] = x[((size_t)(b * OP_ + n0 + (c >> 6))) * 64 + (c & 63)];
    if (tid < 200)
        adj_s[tid] = adj[((size_t)(b * OP_ + n0 + tid / MT)) * MA_ + m0 + tid % MT];
    else if (tid < 200 + 50) {
        const int t = tid - 200;                      // 0..49
        if (t < CN)            eop_s[t]      = ws_eop[b * OP_ + n0 + t];
        else if (t < CN + MT)  ema_s[t - CN] = ws_ema[b * MA_ + m0 + (t - CN)];
    }
    if (tid >= 192 && tid < 256) we_s[tid - 192] = ws_we[tid - 192];
    __syncthreads();

    // ---- scores: one THREAD per pair p = i*MT + j (no cross-lane ops) ----
    if (tid < 200) {
        const float* zr = zf + tid * 68;
        float s = 0.f;
        #pragma unroll 16
        for (int f = 0; f < 64; ++f) s = fmaf(zr[f], we_s[f], s);
        const int i = tid / MT, j = tid % MT;
        float e = s + eop_s[i] + ema_s[j];
        e = (e >= 0.f) ? e : 0.01f * e;               // leaky_relu(0.01)
        sc[tid] = (adj_s[tid] != 0) ? e : NEGM;
    }
    __syncthreads();

    // ---- per-(m,chunk) flash partial: lane = feature, wave owns j = wv+4t ----
    for (int j = wv; j < MT; j += 4) {
        float sv[CN];
        float M = NEGM;
        #pragma unroll
        for (int i = 0; i < CN; ++i) { sv[i] = sc[i * MT + j]; M = fmaxf(M, sv[i]); }
        float L = 0.f, v = 0.f, u = 0.f;
        #pragma unroll
        for (int i = 0; i < CN; ++i) {
            const float p = (sv[i] > -1.0e29f) ? __expf(sv[i] - M) : 0.f;  // explicit mask
            L += p;
            v = fmaf(p, zf[(i * MT + j) * 68 + ln], v);
            u = fmaf(p, xt[i * 64 + ln], u);
        }
        float* pp = part + ((size_t)((b * MA_ + m0 + j) * NCH + ch)) * PSTR;
        pp[ln]      = v;
        pp[64 + ln] = u;
        if (ln == 0) { pp[128] = M; pp[129] = L; }
    }
}

// ---------------- kernel 3: combine + epilogue (wave per (b,m) row) ----------------
__global__ __launch_bounds__(256) void gat_combine(
    const float* __restrict__ y,
    const float* __restrict__ Wop, const float* __restrict__ Wma,
    const float* __restrict__ Wedge,
    const float* __restrict__ part, float* __restrict__ out)
{
    __shared__ float vs[4][64], us[4][64], ys[4][64];
    const int tid = threadIdx.x, wv = tid >> 6, ln = tid & 63;
    const int row = blockIdx.x * 4 + wv;        // bm, grid covers 1600 exactly

    const float* pp = part + (size_t)row * NCH * PSTR;
    float M = NEGM;
    for (int c = 0; c < NCH; ++c) M = fmaxf(M, pp[c * PSTR + 128]);
    float L = 0.f, v = 0.f, u = 0.f;
    #pragma unroll 4
    for (int c = 0; c < NCH; ++c) {
        const float Mc = pp[c * PSTR + 128];
        const float w  = (Mc > -1.0e29f) ? __expf(Mc - M) : 0.f;
        L += w * pp[c * PSTR + 129];
        v += w * pp[c * PSTR + ln];
        u += w * pp[c * PSTR + 64 + ln];
    }
    const float inv = (L > 0.f) ? (1.f / L) : 0.f;
    vs[wv][ln] = v * inv;
    us[wv][ln] = u * inv;
    ys[wv][ln] = y[(size_t)row * 64 + ln];
    __syncthreads();

    float hv = 0.f;
    #pragma unroll 8
    for (int i = 0; i < 64; ++i) {
        hv += vs[wv][i] * Wedge[i * 64 + ln]
            + us[wv][i] * Wop[i * 64 + ln]
            + ys[wv][i] * Wma[i * 64 + ln];
    }
    out[(size_t)row * 64 + ln] = (hv > 0.f) ? hv : (__expf(hv) - 1.f);
}

extern "C" void kernel_launch(void* const* d_in, const int* in_sizes, int n_in,
                              void* d_out, int out_size, void* d_ws, size_t ws_size,
                              hipStream_t stream) {
    const float* x     = (const float*)d_in[0];
    const float* y     = (const float*)d_in[1];
    const float* z     = (const float*)d_in[2];
    const int*   adj   = (const int*)d_in[3];
    const float* Wop   = (const float*)d_in[4];
    const float* Wma   = (const float*)d_in[5];
    const float* Wedge = (const float*)d_in[6];
    const float* att   = (const float*)d_in[7];

    float* ws     = (float*)d_ws;
    float* ws_we  = ws;                              // 64
    float* ws_eop = ws + 64;                         // B*OP = 3200
    float* ws_ema = ws + 64 + B_ * OP_;              // B*MA = 1600
    float* part   = ws + 4864;                       // 1600*40*130 = 8.32M floats

    precompute_k<<<1200, 256, 0, stream>>>(
        x, y, Wop, Wma, Wedge, att, ws_we, ws_eop, ws_ema);
    gat_tile<<<B_ * NCH * NMT, 256, 0, stream>>>(    // 3200 blocks
        x, z, adj, ws_we, ws_eop, ws_ema, part);
    gat_combine<<<(B_ * MA_) / 4, 256, 0, stream>>>(
        y, Wop, Wma, Wedge, part, (float*)d_out);
}

// Round 10
// 295.896 us; speedup vs baseline: 1.0586x; 1.0586x over previous
//
#include <hip/hip_runtime.h>
#include <math.h>

// EdgeGAT: B=8, OP=400, MA=200, F=64. f32 in/out, adj int32.
// Register-streaming flash: one WAVE per (b, m-group of 16, n-chunk of 10).
// Lane = (mq, g): m = m0+mq, f-segment = g*16..g*16+15. Per n-step: 4 coalesced
// float4 z loads (wave reads a contiguous 4KB slab in z's native layout),
// 16-FMA dot + 2 intra-quad DPP reduces, online-softmax rescale in registers.
// No LDS tiles, no __syncthreads in the hot kernel.
#define B_    8
#define OP_   400
#define MA_   200
#define MG    13          // ceil(200/16) m-groups
#define NCH   40          // n-chunks per (b,m)
#define CSTEP 10          // n rows per chunk
#define PSTR  132         // partial: v[64] u[64] M L (+2 pad; 16B-aligned rows)
#define NEGM  -1.0e30f    // finite mask sentinel

// ---------------- kernel 1: precompute (wave-per-row) ----------------
__global__ __launch_bounds__(256) void precompute_k(
    const float* __restrict__ x, const float* __restrict__ y,
    const float* __restrict__ Wop, const float* __restrict__ Wma,
    const float* __restrict__ Wedge, const float* __restrict__ att,
    float* __restrict__ ws_we, float* __restrict__ ws_eop, float* __restrict__ ws_ema)
{
    __shared__ float w_s[192];
    const int tid = threadIdx.x, wv = tid >> 6, ln = tid & 63;
    if (tid < 192) {
        const int which = tid >> 6, i = tid & 63;
        const float* W = (which == 0) ? Wop : ((which == 1) ? Wma : Wedge);
        const float* a = att + which * 64;
        float acc = 0.f;
        #pragma unroll 8
        for (int f = 0; f < 64; ++f) acc = fmaf(W[i * 64 + f], a[f], acc);
        w_s[tid] = acc;
    }
    __syncthreads();
    if (blockIdx.x == 0 && tid < 64) ws_we[tid] = w_s[128 + tid];

    const int row = blockIdx.x * 4 + wv;           // 0 .. 4799
    if (row < B_ * OP_) {
        float s = x[(size_t)row * 64 + ln] * w_s[ln];
        #pragma unroll
        for (int o = 32; o > 0; o >>= 1) s += __shfl_xor(s, o, 64);
        if (ln == 0) ws_eop[row] = s;
    } else if (row < B_ * OP_ + B_ * MA_) {
        const int r2 = row - B_ * OP_;
        float s = y[(size_t)r2 * 64 + ln] * w_s[64 + ln];
        #pragma unroll
        for (int o = 32; o > 0; o >>= 1) s += __shfl_xor(s, o, 64);
        if (ln == 0) ws_ema[r2] = s;
    }
}

// ---------------- kernel 2: register-streaming flash (wave = (b,mg,ch)) ----------------
__global__ __launch_bounds__(256) void gat_stream(
    const float* __restrict__ x, const float* __restrict__ z,
    const int* __restrict__ adj,
    const float* __restrict__ ws_we, const float* __restrict__ ws_eop,
    const float* __restrict__ ws_ema, float* __restrict__ part)
{
    const int tid = threadIdx.x, wv = tid >> 6, ln = tid & 63;
    const int wid = blockIdx.x * 4 + wv;          // 0 .. 4159
    const int b  = wid / (MG * NCH);
    const int rr = wid % (MG * NCH);
    const int mg = rr / NCH, ch = rr % NCH;
    const int n0 = ch * CSTEP;
    const int mq = ln >> 2, g = ln & 3;
    const int m  = mg * 16 + mq;
    const bool mv = (m < MA_);
    const int  mc = mv ? m : (MA_ - 1);           // clamped address

    // this lane's w_e segment (f = g*16 .. g*16+15)
    float we[16];
    #pragma unroll
    for (int k = 0; k < 4; ++k) {
        const float4 q = *(const float4*)(ws_we + g * 16 + k * 4);
        we[k*4+0] = q.x; we[k*4+1] = q.y; we[k*4+2] = q.z; we[k*4+3] = q.w;
    }
    const float ema = ws_ema[b * MA_ + mc];

    float v[16], u[16];
    #pragma unroll
    for (int t = 0; t < 16; ++t) { v[t] = 0.f; u[t] = 0.f; }
    float M = NEGM, L = 0.f;

    #pragma unroll
    for (int i = 0; i < CSTEP; ++i) {
        const int n = n0 + i;
        // z[b, n, m, g*16 .. +15] — wave covers contiguous 4KB slab
        const float* zp = z + (((size_t)(b * OP_ + n)) * MA_ + mc) * 64 + g * 16;
        float zr[16];
        #pragma unroll
        for (int k = 0; k < 4; ++k) {
            const float4 q = *(const float4*)(zp + k * 4);
            zr[k*4+0] = q.x; zr[k*4+1] = q.y; zr[k*4+2] = q.z; zr[k*4+3] = q.w;
        }
        // x[b, n, g*16 .. +15] — replicated across mq, L1/L2 broadcast
        const float* xp = x + ((size_t)(b * OP_ + n)) * 64 + g * 16;
        float xr[16];
        #pragma unroll
        for (int k = 0; k < 4; ++k) {
            const float4 q = *(const float4*)(xp + k * 4);
            xr[k*4+0] = q.x; xr[k*4+1] = q.y; xr[k*4+2] = q.z; xr[k*4+3] = q.w;
        }
        const int a = mv ? adj[((size_t)(b * OP_ + n)) * MA_ + m] : 0;

        float s = 0.f;
        #pragma unroll
        for (int t = 0; t < 16; ++t) s = fmaf(zr[t], we[t], s);
        s += __shfl_xor(s, 1, 64);                // intra-quad, unconditional
        s += __shfl_xor(s, 2, 64);

        float e = s + ws_eop[b * OP_ + n] + ema;
        e = (e >= 0.f) ? e : 0.01f * e;           // leaky_relu(0.01)
        const float se = (a != 0) ? e : NEGM;
        const float Mn = fmaxf(M, se);
        const float al = __expf(M - Mn);          // 1 when both NEGM; 0 when M=NEGM<Mn
        const float p  = (a != 0) ? __expf(se - Mn) : 0.f;
        L = L * al + p;
        #pragma unroll
        for (int t = 0; t < 16; ++t) {
            v[t] = fmaf(v[t], al, p * zr[t]);
            u[t] = fmaf(u[t], al, p * xr[t]);
        }
        M = Mn;
    }

    // ---- write partial for (b, m, ch): v[64] u[64] M L ----
    if (mv) {
        float* pp = part + ((size_t)((b * MA_ + m) * NCH + ch)) * PSTR;
        #pragma unroll
        for (int k = 0; k < 4; ++k) {
            *(float4*)(pp + g * 16 + k * 4) =
                make_float4(v[k*4], v[k*4+1], v[k*4+2], v[k*4+3]);
            *(float4*)(pp + 64 + g * 16 + k * 4) =
                make_float4(u[k*4], u[k*4+1], u[k*4+2], u[k*4+3]);
        }
        if (g == 0) { pp[128] = M; pp[129] = L; }
    }
}

// ---------------- kernel 3: combine + epilogue (wave per (b,m) row) ----------------
__global__ __launch_bounds__(256) void gat_combine(
    const float* __restrict__ y,
    const float* __restrict__ Wop, const float* __restrict__ Wma,
    const float* __restrict__ Wedge,
    const float* __restrict__ part, float* __restrict__ out)
{
    __shared__ float vs[4][64], us[4][64], ys[4][64];
    const int tid = threadIdx.x, wv = tid >> 6, ln = tid & 63;
    const int row = blockIdx.x * 4 + wv;        // bm, grid covers 1600 exactly

    const float* pp = part + (size_t)row * NCH * PSTR;
    float M = NEGM;
    for (int c = 0; c < NCH; ++c) M = fmaxf(M, pp[c * PSTR + 128]);
    float L = 0.f, v = 0.f, u = 0.f;
    #pragma unroll 4
    for (int c = 0; c < NCH; ++c) {
        const float Mc = pp[c * PSTR + 128];
        const float w  = (Mc > -1.0e29f) ? __expf(Mc - M) : 0.f;
        L += w * pp[c * PSTR + 129];
        v += w * pp[c * PSTR + ln];
        u += w * pp[c * PSTR + 64 + ln];
    }
    const float inv = (L > 0.f) ? (1.f / L) : 0.f;
    vs[wv][ln] = v * inv;
    us[wv][ln] = u * inv;
    ys[wv][ln] = y[(size_t)row * 64 + ln];
    __syncthreads();

    float hv = 0.f;
    #pragma unroll 8
    for (int i = 0; i < 64; ++i) {
        hv += vs[wv][i] * Wedge[i * 64 + ln]
            + us[wv][i] * Wop[i * 64 + ln]
            + ys[wv][i] * Wma[i * 64 + ln];
    }
    out[(size_t)row * 64 + ln] = (hv > 0.f) ? hv : (__expf(hv) - 1.f);
}

extern "C" void kernel_launch(void* const* d_in, const int* in_sizes, int n_in,
                              void* d_out, int out_size, void* d_ws, size_t ws_size,
                              hipStream_t stream) {
    const float* x     = (const float*)d_in[0];
    const float* y     = (const float*)d_in[1];
    const float* z     = (const float*)d_in[2];
    const int*   adj   = (const int*)d_in[3];
    const float* Wop   = (const float*)d_in[4];
    const float* Wma   = (const float*)d_in[5];
    const float* Wedge = (const float*)d_in[6];
    const float* att   = (const float*)d_in[7];

    float* ws     = (float*)d_ws;
    float* ws_we  = ws;                              // 64
    float* ws_eop = ws + 64;                         // B*OP = 3200
    float* ws_ema = ws + 64 + B_ * OP_;              // B*MA = 1600
    float* part   = ws + 4864;                       // 64000 * 132 floats = 33.8 MB

    precompute_k<<<1200, 256, 0, stream>>>(
        x, y, Wop, Wma, Wedge, att, ws_we, ws_eop, ws_ema);
    gat_stream<<<(B_ * MG * NCH) / 4, 256, 0, stream>>>(   // 1040 blocks, 4160 waves
        x, z, adj, ws_we, ws_eop, ws_ema, part);
    gat_combine<<<(B_ * MA_) / 4, 256, 0, stream>>>(
        y, Wop, Wma, Wedge, part, (float*)d_out);
}

// Round 11
// 291.137 us; speedup vs baseline: 1.0759x; 1.0163x over previous
//
#include <hip/hip_runtime.h>
#include <math.h>

// EdgeGAT: B=8, OP=400, MA=200, F=64. f32 in/out, adj int32.
// z read ONCE, fully coalesced in native [b][n][m][f] layout.
// Block = (b, n-chunk CN=10, m-tile MT=10): 25.6KB z-tile -> ~31KB LDS total
// -> 5 blocks/CU (R9's 59KB tile capped at 2 -> 20% occupancy, latency-bound).
// Thread-per-pair scalar scores, per-(m,chunk) flash partials, combine rescales.
#define B_   8
#define OP_  400
#define MA_  200
#define CN   10           // n rows per chunk
#define MT   10           // m cols per tile
#define NCH  40           // OP_/CN chunks per (b,m)
#define NMT  20           // MA_/MT m-tiles
#define PSTR 130          // partial: v[64] u[64] M L
#define NEGM -1.0e30f     // finite mask sentinel

// ---------------- kernel 1: precompute (wave-per-row) ----------------
// w_e = W_edge@a_edge ; e_op[b,n] = x[b,n,:].(W_op@a_op) ; e_ma[b,m] = y[b,m,:].(W_ma@a_ma)
__global__ __launch_bounds__(256) void precompute_k(
    const float* __restrict__ x, const float* __restrict__ y,
    const float* __restrict__ Wop, const float* __restrict__ Wma,
    const float* __restrict__ Wedge, const float* __restrict__ att,
    float* __restrict__ ws_we, float* __restrict__ ws_eop, float* __restrict__ ws_ema)
{
    __shared__ float w_s[192];
    const int tid = threadIdx.x, wv = tid >> 6, ln = tid & 63;
    if (tid < 192) {
        const int which = tid >> 6, i = tid & 63;
        const float* W = (which == 0) ? Wop : ((which == 1) ? Wma : Wedge);
        const float* a = att + which * 64;
        float acc = 0.f;
        #pragma unroll 8
        for (int f = 0; f < 64; ++f) acc = fmaf(W[i * 64 + f], a[f], acc);
        w_s[tid] = acc;
    }
    __syncthreads();
    if (blockIdx.x == 0 && tid < 64) ws_we[tid] = w_s[128 + tid];

    const int row = blockIdx.x * 4 + wv;           // 0 .. 4799
    if (row < B_ * OP_) {
        float s = x[(size_t)row * 64 + ln] * w_s[ln];
        #pragma unroll
        for (int o = 32; o > 0; o >>= 1) s += __shfl_xor(s, o, 64);
        if (ln == 0) ws_eop[row] = s;
    } else if (row < B_ * OP_ + B_ * MA_) {
        const int r2 = row - B_ * OP_;
        float s = y[(size_t)r2 * 64 + ln] * w_s[64 + ln];
        #pragma unroll
        for (int o = 32; o > 0; o >>= 1) s += __shfl_xor(s, o, 64);
        if (ln == 0) ws_ema[r2] = s;
    }
}

// ---------------- kernel 2: z-tile pass (block = (b, chunk, m-tile)) ----------------
__global__ __launch_bounds__(256) void gat_tile(
    const float* __restrict__ x, const float* __restrict__ z,
    const int* __restrict__ adj,
    const float* __restrict__ ws_we, const float* __restrict__ ws_eop,
    const float* __restrict__ ws_ema, float* __restrict__ part)
{
    __shared__ float4 z4[100 * 17];   // 27200 B: row p=i*MT+j, 17 float4 (68 f) stride
    __shared__ float  sc[100];        // scores, index i*MT+j
    __shared__ float  xt[CN * 64];    // x tile
    __shared__ float  we_s[64];       // w_e
    __shared__ float  eop_s[CN];
    __shared__ float  ema_s[MT];
    __shared__ int    adj_s[100];

    const float* zf = (const float*)z4;   // scalar view, row stride 68 floats

    const int tid = threadIdx.x, wv = tid >> 6, ln = tid & 63;
    const int bid = blockIdx.x;
    const int mt = bid % NMT;
    const int ch = (bid / NMT) % NCH;
    const int b  = bid / (NMT * NCH);
    const int n0 = ch * CN, m0 = mt * MT;

    // ---- stage z tile: slice i = 640 contiguous floats (10 m x 64 f) ----
    for (int c = tid; c < CN * MT * 16; c += 256) {   // 1600 float4
        const int i = c / (MT * 16);                  // n-row in chunk
        const int r = c % (MT * 16);                  // float4 within slice
        const int j = r / 16;                         // m-col in tile
        const int k = r % 16;                         // float4 within row
        const float* zs = z + (((size_t)(b * OP_ + n0 + i)) * MA_ + m0) * 64;
        z4[(i * MT + j) * 17 + k] = *(const float4*)(zs + r * 4);
    }
    for (int c = tid; c < CN * 64; c += 256)
        xt[c] = x[((size_t)(b * OP_ + n0 + (c >> 6))) * 64 + (c & 63)];
    if (tid < 100)
        adj_s[tid] = adj[((size_t)(b * OP_ + n0 + tid / MT)) * MA_ + m0 + tid % MT];
    else if (tid < 100 + 20) {
        const int t = tid - 100;                      // 0..19
        if (t < CN)           eop_s[t]      = ws_eop[b * OP_ + n0 + t];
        else                  ema_s[t - CN] = ws_ema[b * MA_ + m0 + (t - CN)];
    }
    if (tid >= 192 && tid < 256) we_s[tid - 192] = ws_we[tid - 192];
    __syncthreads();

    // ---- scores: one THREAD per pair p = i*MT + j (no cross-lane ops) ----
    if (tid < 100) {
        const float* zr = zf + tid * 68;
        float s = 0.f;
        #pragma unroll 16
        for (int f = 0; f < 64; ++f) s = fmaf(zr[f], we_s[f], s);
        const int i = tid / MT, j = tid % MT;
        float e = s + eop_s[i] + ema_s[j];
        e = (e >= 0.f) ? e : 0.01f * e;               // leaky_relu(0.01)
        sc[tid] = (adj_s[tid] != 0) ? e : NEGM;
    }
    __syncthreads();

    // ---- per-(m,chunk) flash partial: lane = feature, wave owns j = wv+4t ----
    for (int j = wv; j < MT; j += 4) {
        float sv[CN];
        float M = NEGM;
        #pragma unroll
        for (int i = 0; i < CN; ++i) { sv[i] = sc[i * MT + j]; M = fmaxf(M, sv[i]); }
        float L = 0.f, v = 0.f, u = 0.f;
        #pragma unroll
        for (int i = 0; i < CN; ++i) {
            const float p = (sv[i] > -1.0e29f) ? __expf(sv[i] - M) : 0.f;  // explicit mask
            L += p;
            v = fmaf(p, zf[(i * MT + j) * 68 + ln], v);
            u = fmaf(p, xt[i * 64 + ln], u);
        }
        float* pp = part + ((size_t)((b * MA_ + m0 + j) * NCH + ch)) * PSTR;
        pp[ln]      = v;
        pp[64 + ln] = u;
        if (ln == 0) { pp[128] = M; pp[129] = L; }
    }
}

// ---------------- kernel 3: combine + epilogue (wave per (b,m) row) ----------------
__global__ __launch_bounds__(256) void gat_combine(
    const float* __restrict__ y,
    const float* __restrict__ Wop, const float* __restrict__ Wma,
    const float* __restrict__ Wedge,
    const float* __restrict__ part, float* __restrict__ out)
{
    __shared__ float vs[4][64], us[4][64], ys[4][64];
    const int tid = threadIdx.x, wv = tid >> 6, ln = tid & 63;
    const int row = blockIdx.x * 4 + wv;        // bm, grid covers 1600 exactly

    const float* pp = part + (size_t)row * NCH * PSTR;
    float M = NEGM;
    for (int c = 0; c < NCH; ++c) M = fmaxf(M, pp[c * PSTR + 128]);
    float L = 0.f, v = 0.f, u = 0.f;
    #pragma unroll 4
    for (int c = 0; c < NCH; ++c) {
        const float Mc = pp[c * PSTR + 128];
        const float w  = (Mc > -1.0e29f) ? __expf(Mc - M) : 0.f;
        L += w * pp[c * PSTR + 129];
        v += w * pp[c * PSTR + ln];
        u += w * pp[c * PSTR + 64 + ln];
    }
    const float inv = (L > 0.f) ? (1.f / L) : 0.f;
    vs[wv][ln] = v * inv;
    us[wv][ln] = u * inv;
    ys[wv][ln] = y[(size_t)row * 64 + ln];
    __syncthreads();

    float hv = 0.f;
    #pragma unroll 8
    for (int i = 0; i < 64; ++i) {
        hv += vs[wv][i] * Wedge[i * 64 + ln]
            + us[wv][i] * Wop[i * 64 + ln]
            + ys[wv][i] * Wma[i * 64 + ln];
    }
    out[(size_t)row * 64 + ln] = (hv > 0.f) ? hv : (__expf(hv) - 1.f);
}

extern "C" void kernel_launch(void* const* d_in, const int* in_sizes, int n_in,
                              void* d_out, int out_size, void* d_ws, size_t ws_size,
                              hipStream_t stream) {
    const float* x     = (const float*)d_in[0];
    const float* y     = (const float*)d_in[1];
    const float* z     = (const float*)d_in[2];
    const int*   adj   = (const int*)d_in[3];
    const float* Wop   = (const float*)d_in[4];
    const float* Wma   = (const float*)d_in[5];
    const float* Wedge = (const float*)d_in[6];
    const float* att   = (const float*)d_in[7];

    float* ws     = (float*)d_ws;
    float* ws_we  = ws;                              // 64
    float* ws_eop = ws + 64;                         // B*OP = 3200
    float* ws_ema = ws + 64 + B_ * OP_;              // B*MA = 1600
    float* part   = ws + 4864;                       // 1600*40*130 = 8.32M floats

    precompute_k<<<1200, 256, 0, stream>>>(
        x, y, Wop, Wma, Wedge, att, ws_we, ws_eop, ws_ema);
    gat_tile<<<B_ * NCH * NMT, 256, 0, stream>>>(    // 6400 blocks
        x, z, adj, ws_we, ws_eop, ws_ema, part);
    gat_combine<<<(B_ * MA_) / 4, 256, 0, stream>>>(
        y, Wop, Wma, Wedge, part, (float*)d_out);
}